// Round 7
// baseline (341.479 us; speedup 1.0000x reference)
//
#include <hip/hip_runtime.h>

// GatedQueryAttLayer on MI355X (gfx950)
// B=16, S=512, E=1024, H=16, DK=64
// Pipeline: prep (inp->bf16 + W^T cvt) ; fused QKV bf16-MFMA GEMM ;
//           FUSED gating+flash-attention (gate computed in-kernel per tile;
//           no separate gate kernel, no gated q/k materialization).
// Workspace: 70 MB.

typedef __bf16 bf16;
typedef __bf16 bf16x8 __attribute__((ext_vector_type(8)));
typedef __bf16 bf16x4 __attribute__((ext_vector_type(4)));
typedef float  f32x4  __attribute__((ext_vector_type(4)));

#define MFMA16(a,b,c) __builtin_amdgcn_mfma_f32_16x16x32_bf16((a),(b),(c),0,0,0)

#define GLL16(gp, lp)                                                          \
  __builtin_amdgcn_global_load_lds(                                            \
      (__attribute__((address_space(1))) void*)(void*)(gp),                    \
      (__attribute__((address_space(3))) void*)(lp), 16, 0, 0)

// --------------------------------------------- prep: inp cvt + weight cvt/T
__global__ __launch_bounds__(256) void k_prep(const float* __restrict__ in,
                                              bf16* __restrict__ Xb,
                                              const float* __restrict__ Wq,
                                              const float* __restrict__ Wk,
                                              const float* __restrict__ Wv,
                                              bf16* __restrict__ WT) {
  __shared__ float tile[32][33];
  const int bx = blockIdx.x, t = threadIdx.x;
  if (bx < 8192) {                       // conv: fp32 -> bf16, 4 elems/thread
    int i = bx * 256 + t;
    float4 v = ((const float4*)in)[i];
    bf16x4 o;
    o[0] = (bf16)v.x; o[1] = (bf16)v.y; o[2] = (bf16)v.z; o[3] = (bf16)v.w;
    ((bf16x4*)Xb)[i] = o;
  } else {                               // weight transpose + cvt
    int r = bx - 8192;
    int mat = r >> 10; r &= 1023;
    int kb = r >> 5, nb = r & 31;
    const float* W = (mat == 0) ? Wq : ((mat == 1) ? Wk : Wv);
    bf16* O = WT + (size_t)mat * (1024 * 1024);
    const int tr = t >> 3, tc = (t & 7) * 4;
    float4 v = *(const float4*)&W[(size_t)(kb * 32 + tr) * 1024 + nb * 32 + tc];
    tile[tr][tc] = v.x; tile[tr][tc + 1] = v.y;
    tile[tr][tc + 2] = v.z; tile[tr][tc + 3] = v.w;
    __syncthreads();
    bf16x4 o;
    o[0] = (bf16)tile[tc][tr];     o[1] = (bf16)tile[tc + 1][tr];
    o[2] = (bf16)tile[tc + 2][tr]; o[3] = (bf16)tile[tc + 3][tr];
    *(bf16x4*)&O[(size_t)(nb * 32 + tr) * 1024 + kb * 32 + tc] = o;
  }
}

// -------------------------------------------------- fused QKV projection GEMM
// r3 variant (plateau per A/Bs r2-r4: 85.7 us). Single-buffer, XOR-swizzled
// staging, swapped-operand MFMA (C transposed -> vectorized stores).
__global__ __launch_bounds__(256) void k_proj(const bf16* __restrict__ X,
                                              const bf16* __restrict__ WT,
                                              const float* __restrict__ bq,
                                              const float* __restrict__ bk,
                                              const float* __restrict__ bv,
                                              bf16* __restrict__ qw,
                                              bf16* __restrict__ kw,
                                              bf16* __restrict__ vt) {
  __shared__ bf16 As[128 * 32];
  __shared__ bf16 Bs[128 * 32];
  const int tid = threadIdx.x;
  const int m0 = blockIdx.x * 128;
  const int by = blockIdx.y;
  const int mat = by >> 3;             // 0=q,1=k,2=v
  const int n0 = (by & 7) * 128;
  const bf16* Wt = WT + (size_t)mat * (1024 * 1024);
  const float* bias = (mat == 0) ? bq : ((mat == 1) ? bk : bv);
  const int l = tid & 63, w = tid >> 6;
  const int wm = w >> 1, wn = w & 1;
  const int l4 = l & 15, q8 = l >> 4;
  const int rowa = wm * 64 + l4;
  const int rowb = wn * 64 + l4;
  const int ca = q8 ^ ((rowa + (rowa >> 2)) & 3);
  const int cb = q8 ^ ((rowb + (rowb >> 2)) & 3);

  f32x4 acc[4][4] = {};
  for (int kt = 0; kt < 1024; kt += 32) {
    __syncthreads();
#pragma unroll
    for (int i = 0; i < 2; ++i) {
      int chunk = i * 256 + tid;
      int srow = chunk >> 2, cs = chunk & 3;
      int cg = cs ^ ((srow + (srow >> 2)) & 3);
      GLL16(X  + (size_t)(m0 + srow) * 1024 + kt + cg * 8, As + chunk * 8);
      GLL16(Wt + (size_t)(n0 + srow) * 1024 + kt + cg * 8, Bs + chunk * 8);
    }
    __syncthreads();
    bf16x8 a[4], b[4];
#pragma unroll
    for (int i = 0; i < 4; ++i)
      a[i] = *(const bf16x8*)&As[(rowa + i * 16) * 32 + ca * 8];
#pragma unroll
    for (int j = 0; j < 4; ++j)
      b[j] = *(const bf16x8*)&Bs[(rowb + j * 16) * 32 + cb * 8];
#pragma unroll
    for (int i = 0; i < 4; ++i)
#pragma unroll
      for (int j = 0; j < 4; ++j)
        acc[i][j] = MFMA16(b[j], a[i], acc[i][j]);   // swapped: C transposed
  }
#pragma unroll
  for (int i = 0; i < 4; ++i) {
    int m = m0 + wm * 64 + i * 16 + l4;    // 0..8191 = b*512+s
    int b_ = m >> 9, s = m & 511;
#pragma unroll
    for (int j = 0; j < 4; ++j) {
      int nb = n0 + wn * 64 + j * 16 + q8 * 4;   // 4 consecutive n
      if (mat == 2) {
#pragma unroll
        for (int r = 0; r < 4; ++r) {
          int n = nb + r, h = n >> 6, d = n & 63;
          vt[((size_t)(b_ * 16 + h) * 64 + d) * 512 + s] =
              (bf16)(acc[i][j][r] + bias[n]);
        }
      } else {
        float4 bb = *(const float4*)&bias[nb];
        bf16x4 o;
        o[0] = (bf16)(acc[i][j][0] + bb.x);
        o[1] = (bf16)(acc[i][j][1] + bb.y);
        o[2] = (bf16)(acc[i][j][2] + bb.z);
        o[3] = (bf16)(acc[i][j][3] + bb.w);
        bf16* dst = (mat == 0) ? qw : kw;
        *(bf16x4*)&dst[(size_t)m * 1024 + nb] = o;
      }
    }
  }
}

// ---------------------------------------------------------------- helpers
static __device__ __forceinline__ bf16x8 gathW(const float* __restrict__ W,
                                               int stride, int n, int k0) {
  bf16x8 r;
#pragma unroll
  for (int j = 0; j < 8; ++j) r[j] = (bf16)W[(k0 + j) * stride + n];
  return r;
}
static __device__ __forceinline__ bf16x8 mul8(bf16x8 a, bf16x8 b, float s) {
  bf16x8 r;
#pragma unroll
  for (int e = 0; e < 8; ++e) r[e] = (bf16)((float)a[e] * (float)b[e] * s);
  return r;
}

// ------------------------------------------- fused gating + flash attention
// Block = 256 thr (4 waves) = 128 q-rows of one (b,h); XCD swizzle as r6.
// Per 128-token group (own queries once, then each 128-key tile):
//   fq/fk A-frags direct from global qw/kw; gate-weight B-frags gathered
//   once into regs (L1-hot fp32 source); G round-trips sG with OWN-WAVE rows
//   (no barrier); sigmoid(M) -> Ms, one publish barrier; gated K applied
//   in-register at score-frag build. Gated Q folded into qf (x log2e/8).
// LDS: sG 18432 + Ms 18432 + Pb 10240 = 47104 B. 2 syncs per K-tile.
__global__ __launch_bounds__(256, 2) void k_attn(const bf16* __restrict__ qw,
                                                 const bf16* __restrict__ kw,
                                                 const bf16* __restrict__ vt,
                                                 const float* __restrict__ Wfq,
                                                 const float* __restrict__ bfq,
                                                 const float* __restrict__ Wfk,
                                                 const float* __restrict__ bfk,
                                                 const float* __restrict__ Wfg,
                                                 const float* __restrict__ bfg,
                                                 float* __restrict__ out) {
  __shared__ bf16 sG[128 * 72];
  __shared__ bf16 Ms[128 * 72];
  __shared__ bf16 Pb[4][32 * 40];
  const int tid = threadIdx.x, w = tid >> 6, l = tid & 63;
  const int l4 = l & 15, q8 = l >> 4;
  const int bx = blockIdx.x;
  const int slot = bx >> 3, qc = slot & 3;
  const int bh = (bx & 7) + 8 * (slot >> 2);
  const int b_ = bh >> 4, h = bh & 15;
  const int rbase = w * 32;
  bf16* Pw = &Pb[w][0];

  // gate-weight fragments (resident; source is 48 KB fp32, L1/L2-hot)
  bf16x8 wq[4][2], wk[4][2], wgk[4][2];
  float bq_l[4], bk_l[4], bgk_l[4];
#pragma unroll
  for (int j = 0; j < 4; ++j) {
    int n = j * 16 + l4;
#pragma unroll
    for (int kk = 0; kk < 2; ++kk) {
      int k0 = kk * 32 + q8 * 8;
      wq[j][kk]  = gathW(Wfq, 64, n, k0);
      wk[j][kk]  = gathW(Wfk, 64, n, k0);
      wgk[j][kk] = gathW(Wfg, 128, 64 + n, k0);
    }
    bq_l[j] = bfq[n]; bk_l[j] = bfk[n]; bgk_l[j] = bfg[64 + n];
  }

  // -------- gate step for token group s0..s0+127; writes Ms rows (own wave)
  // half=0: q-half of M (Wfg cols 0..63, bias bfg[0..64))  [phase A]
  // half=1: k-half of M (resident wgk/bgk)                 [per K-tile]
  // aqs returns the raw q A-frags (reused for qf build in phase A).
  auto gate_step = [&](int s0, const bf16x8 wg[4][2], const float* bg_l,
                       bf16x8 aqs[2][2]) {
    bf16x8 aks[2][2];
#pragma unroll
    for (int i = 0; i < 2; ++i)
#pragma unroll
      for (int kk = 0; kk < 2; ++kk) {
        size_t off = (((size_t)b_ * 512 + s0 + rbase + i * 16 + l4) * 16 + h)
                         * 64 + kk * 32 + q8 * 8;
        aqs[i][kk] = *(const bf16x8*)&qw[off];
        aks[i][kk] = *(const bf16x8*)&kw[off];
      }
    f32x4 fqc[2][4] = {}, fkc[2][4] = {};
#pragma unroll
    for (int j = 0; j < 4; ++j)
#pragma unroll
      for (int i = 0; i < 2; ++i) {
        fqc[i][j] = MFMA16(aqs[i][0], wq[j][0], fqc[i][j]);
        fqc[i][j] = MFMA16(aqs[i][1], wq[j][1], fqc[i][j]);
        fkc[i][j] = MFMA16(aks[i][0], wk[j][0], fkc[i][j]);
        fkc[i][j] = MFMA16(aks[i][1], wk[j][1], fkc[i][j]);
      }
    // G -> sG (own-wave rows; no barrier needed)
#pragma unroll
    for (int j = 0; j < 4; ++j)
#pragma unroll
      for (int i = 0; i < 2; ++i)
#pragma unroll
        for (int r = 0; r < 4; ++r) {
          int row = rbase + i * 16 + q8 * 4 + r;
          float g = (fqc[i][j][r] + bq_l[j]) * (fkc[i][j][r] + bk_l[j]);
          sG[row * 72 + j * 16 + l4] = (bf16)g;
        }
    bf16x8 ag[2][2];
#pragma unroll
    for (int i = 0; i < 2; ++i)
#pragma unroll
      for (int kk = 0; kk < 2; ++kk)
        ag[i][kk] =
            *(const bf16x8*)&sG[(rbase + i * 16 + l4) * 72 + kk * 32 + q8 * 8];
    f32x4 mc[2][4] = {};
#pragma unroll
    for (int jj = 0; jj < 4; ++jj)
#pragma unroll
      for (int i = 0; i < 2; ++i) {
        mc[i][jj] = MFMA16(ag[i][0], wg[jj][0], mc[i][jj]);
        mc[i][jj] = MFMA16(ag[i][1], wg[jj][1], mc[i][jj]);
      }
#pragma unroll
    for (int jj = 0; jj < 4; ++jj)
#pragma unroll
      for (int i = 0; i < 2; ++i)
#pragma unroll
        for (int r = 0; r < 4; ++r) {
          int row = rbase + i * 16 + q8 * 4 + r;
          float m = mc[i][jj][r] + bg_l[jj];
          Ms[row * 72 + jj * 16 + l4] = (bf16)(1.0f / (1.0f + __expf(-m)));
        }
  };

  // -------- phase A: gate own queries, build qf (x M_q x log2e/8)
  const float SC = 0.18033688011112042f;  // log2(e)/8
  bf16x8 qf[2][2];
  {
    bf16x8 wgq[4][2];
    float bgq_l[4];
#pragma unroll
    for (int j = 0; j < 4; ++j) {
      int n = j * 16 + l4;
#pragma unroll
      for (int kk = 0; kk < 2; ++kk)
        wgq[j][kk] = gathW(Wfg, 128, n, kk * 32 + q8 * 8);
      bgq_l[j] = bfg[n];
    }
    bf16x8 aqs[2][2];
    gate_step(qc * 128, wgq, bgq_l, aqs);
    // own-wave Ms rows -> no barrier
#pragma unroll
    for (int i = 0; i < 2; ++i)
#pragma unroll
      for (int kk = 0; kk < 2; ++kk) {
        bf16x8 mr = *(const bf16x8*)&Ms[(rbase + i * 16 + l4) * 72 +
                                        kk * 32 + q8 * 8];
        qf[i][kk] = mul8(aqs[i][kk], mr, SC);
      }
  }

  f32x4 o[2][4] = {};
  float mrun[2][4], lrun[2][4];
#pragma unroll
  for (int i = 0; i < 2; ++i)
#pragma unroll
    for (int r = 0; r < 4; ++r) { mrun[i][r] = -3.0e38f; lrun[i][r] = 0.0f; }

  for (int t = 0; t < 4; ++t) {
    __syncthreads();                 // prior tile's cross-wave Ms reads done
    {
      bf16x8 dummy[2][2];
      gate_step(t * 128, wgk, bgk_l, dummy);   // Ms rows <- sigmoid K-half
    }
    __syncthreads();                 // Ms published to all waves

    // scores: D[q (2x16)][key (8x16)], gated K built in-register
    f32x4 sc[2][8];
    const f32x4 fz = {};
#pragma unroll
    for (int c = 0; c < 8; ++c) {
      size_t koff = (((size_t)b_ * 512 + t * 128 + c * 16 + l4) * 16 + h) * 64;
      bf16x8 kr0 = *(const bf16x8*)&kw[koff + q8 * 8];
      bf16x8 kr1 = *(const bf16x8*)&kw[koff + 32 + q8 * 8];
      bf16x8 m0 = *(const bf16x8*)&Ms[(c * 16 + l4) * 72 + q8 * 8];
      bf16x8 m1 = *(const bf16x8*)&Ms[(c * 16 + l4) * 72 + 32 + q8 * 8];
      bf16x8 kb0 = mul8(kr0, m0, 1.0f);
      bf16x8 kb1 = mul8(kr1, m1, 1.0f);
      sc[0][c] = MFMA16(qf[0][0], kb0, fz);
      sc[1][c] = MFMA16(qf[1][0], kb0, fz);
      sc[0][c] = MFMA16(qf[0][1], kb1, sc[0][c]);
      sc[1][c] = MFMA16(qf[1][1], kb1, sc[1][c]);
    }

    // online softmax (exp2 domain); row stats shared by 16-lane groups
#pragma unroll
    for (int i = 0; i < 2; ++i) {
      float al[4];
#pragma unroll
      for (int r = 0; r < 4; ++r) {
        float mx = sc[i][0][r];
#pragma unroll
        for (int c = 1; c < 8; ++c) mx = fmaxf(mx, sc[i][c][r]);
        mx = fmaxf(mx, __shfl_xor(mx, 1));
        mx = fmaxf(mx, __shfl_xor(mx, 2));
        mx = fmaxf(mx, __shfl_xor(mx, 4));
        mx = fmaxf(mx, __shfl_xor(mx, 8));
        float mn = fmaxf(mrun[i][r], mx);
        al[r] = exp2f(mrun[i][r] - mn);
        mrun[i][r] = mn;
        float sm = 0.0f;
#pragma unroll
        for (int c = 0; c < 8; ++c) {
          float p = exp2f(sc[i][c][r] - mn);
          sc[i][c][r] = p;
          sm += p;
        }
        sm += __shfl_xor(sm, 1); sm += __shfl_xor(sm, 2);
        sm += __shfl_xor(sm, 4); sm += __shfl_xor(sm, 8);
        lrun[i][r] = lrun[i][r] * al[r] + sm;
      }
#pragma unroll
      for (int f = 0; f < 4; ++f)
#pragma unroll
        for (int r = 0; r < 4; ++r) o[i][f][r] *= al[r];
    }

    // PV: P -> per-wave LDS chunk -> A-frags; V^T B-frags direct from global
#pragma unroll
    for (int kk2 = 0; kk2 < 4; ++kk2) {
#pragma unroll
      for (int i = 0; i < 2; ++i)
#pragma unroll
        for (int cc = 0; cc < 2; ++cc) {
          int c = kk2 * 2 + cc;
#pragma unroll
          for (int r = 0; r < 4; ++r)
            Pw[(i * 16 + q8 * 4 + r) * 40 + cc * 16 + l4] = (bf16)sc[i][c][r];
        }
      bf16x8 pa0 = *(const bf16x8*)&Pw[(l4) * 40 + q8 * 8];
      bf16x8 pa1 = *(const bf16x8*)&Pw[(16 + l4) * 40 + q8 * 8];
#pragma unroll
      for (int f = 0; f < 4; ++f) {
        bf16x8 vb = *(const bf16x8*)
            &vt[((size_t)bh * 64 + f * 16 + l4) * 512 + t * 128 +
                kk2 * 32 + q8 * 8];
        o[0][f] = MFMA16(pa0, vb, o[0][f]);
        o[1][f] = MFMA16(pa1, vb, o[1][f]);
      }
    }
  }

  // epilogue: normalize, write [B,S,E] fp32
#pragma unroll
  for (int i = 0; i < 2; ++i)
#pragma unroll
    for (int r = 0; r < 4; ++r) {
      int srow = qc * 128 + w * 32 + i * 16 + q8 * 4 + r;
      float inv = 1.0f / lrun[i][r];
#pragma unroll
      for (int f = 0; f < 4; ++f)
        out[(((size_t)b_ * 512 + srow) * 16 + h) * 64 + f * 16 + l4] =
            o[i][f][r] * inv;
    }
}

// ---------------------------------------------------------------- launcher
extern "C" void kernel_launch(void* const* d_in, const int* in_sizes, int n_in,
                              void* d_out, int out_size, void* d_ws,
                              size_t ws_size, hipStream_t stream) {
  (void)in_sizes; (void)n_in; (void)out_size; (void)ws_size;
  const float* inp = (const float*)d_in[0];
  const float* Wq  = (const float*)d_in[1];
  const float* bq  = (const float*)d_in[2];
  const float* Wk  = (const float*)d_in[3];
  const float* bk  = (const float*)d_in[4];
  const float* Wv  = (const float*)d_in[5];
  const float* bv  = (const float*)d_in[6];
  const float* Wfq = (const float*)d_in[7];
  const float* bfq = (const float*)d_in[8];
  const float* Wfk = (const float*)d_in[9];
  const float* bfk = (const float*)d_in[10];
  const float* Wfg = (const float*)d_in[11];
  const float* bfg = (const float*)d_in[12];
  float* out = (float*)d_out;

  char* ws = (char*)d_ws;
  bf16* Xb = (bf16*)(ws);                                // 16 MB
  bf16* WT = (bf16*)(ws + 16777216);                     // 6 MB (3x W^T)
  bf16* qw = (bf16*)(ws + 16777216 + 6291456);           // 16 MB [B,S,H,DK]
  bf16* kw = qw + 8388608;                               // 16 MB
  bf16* vt = kw + 8388608;                               // 16 MB [B,H,DK,S]

  k_prep<<<11264, 256, 0, stream>>>(inp, Xb, Wq, Wk, Wv, WT);
  k_proj<<<dim3(64, 24), 256, 0, stream>>>(Xb, WT, bq, bk, bv, qw, kw, vt);
  k_attn<<<1024, 256, 0, stream>>>(qw, kw, vt, Wfq, bfq, Wfk, bfk, Wfg, bfg,
                                   out);
}